// Round 5
// baseline (133.858 us; speedup 1.0000x reference)
//
#include <hip/hip_runtime.h>

#define NN 4096
#define NT 1024

__global__ __launch_bounds__(NT)
void DistanceNMS_kernel(const float* __restrict__ peaks, float* __restrict__ out)
{
    // ---- LDS (~152 KB) ----
    __shared__ uint4 pts[NN];                   // 64K  {x_bits, y_bits, kb, state} by orig idx
    __shared__ unsigned cellidx[4096];          // 16K  count -> excl start -> end
    __shared__ unsigned buckidx[4096];          // 16K  count -> excl start -> end
    __shared__ unsigned short cellpts[NN];      //  8K  orig idx grouped by cell
    __shared__ unsigned long long sortbuf[NN];  // 32K  (kb<<32)|oi
    __shared__ unsigned short wlA[NN];          //  8K  worklist ping
    __shared__ unsigned short wlB[NN];          //  8K  worklist pong
    __shared__ unsigned wavesumA[16], wavesumB[16];
    __shared__ unsigned wlcnt;

    const int tid  = threadIdx.x;
    const int lane = tid & 63;
    const int wv   = tid >> 6;
    const int b    = blockIdx.x;
    const float* bp = peaks + (size_t)b * NN * 3;
    float* bo = out + (size_t)b * NN * 3;

    volatile unsigned* vstate = ((volatile unsigned*)pts) + 3;   // stride 4, word 3 of each uint4

    // ---- phase 0: zero counters ----
    {
        int t4 = tid << 2;
        cellidx[t4] = 0; cellidx[t4+1] = 0; cellidx[t4+2] = 0; cellidx[t4+3] = 0;
        buckidx[t4] = 0; buckidx[t4+1] = 0; buckidx[t4+2] = 0; buckidx[t4+3] = 0;
        if (tid == 0) wlcnt = 0;
    }
    __syncthreads();                                           // B1

    // ---- phase 1: load + count ----
    for (int j = tid; j < NN; j += NT) {
        float x = bp[j*3+0], y = bp[j*3+1], cf = bp[j*3+2];
        unsigned kbv = ~__float_as_uint(cf);    // conf>=0 -> ascending kb == descending conf
        pts[j] = make_uint4(__float_as_uint(x), __float_as_uint(y), kbv, 0u);
        int cx = min((int)(x * 0.125f), 63);
        int cy = min((int)(y * 0.125f), 63);
        atomicAdd(&cellidx[(cy << 6) | cx], 1u);
        int bk = 4095 - min((int)__fmul_rn(cf, 4096.0f), 4095);  // monotone bucketing
        atomicAdd(&buckidx[bk], 1u);
    }
    __syncthreads();                                           // B2

    // ---- phase 2: dual in-place exclusive scan ----
    {
        int t4 = tid << 2;
        unsigned a0=cellidx[t4], a1=cellidx[t4+1], a2=cellidx[t4+2], a3=cellidx[t4+3];
        unsigned b0=buckidx[t4], b1=buckidx[t4+1], b2=buckidx[t4+2], b3=buckidx[t4+3];
        unsigned sa = a0+a1+a2+a3, sb = b0+b1+b2+b3;
        unsigned ia = sa, ib = sb;
        for (int off = 1; off < 64; off <<= 1) {
            unsigned na = __shfl_up(ia, off);
            unsigned nb = __shfl_up(ib, off);
            if (lane >= off) { ia += na; ib += nb; }
        }
        if (lane == 63) { wavesumA[wv] = ia; wavesumB[wv] = ib; }
        __syncthreads();                                       // B3
        if (tid == 0) {
            unsigned acc = 0;
            for (int i = 0; i < 16; ++i) { unsigned t = wavesumA[i]; wavesumA[i] = acc; acc += t; }
            acc = 0;
            for (int i = 0; i < 16; ++i) { unsigned t = wavesumB[i]; wavesumB[i] = acc; acc += t; }
        }
        __syncthreads();                                       // B4
        unsigned baseA = wavesumA[wv] + (ia - sa);
        unsigned baseB = wavesumB[wv] + (ib - sb);
        cellidx[t4]=baseA; cellidx[t4+1]=baseA+a0; cellidx[t4+2]=baseA+a0+a1; cellidx[t4+3]=baseA+a0+a1+a2;
        buckidx[t4]=baseB; buckidx[t4+1]=baseB+b0; buckidx[t4+2]=baseB+b0+b1; buckidx[t4+3]=baseB+b0+b1+b2;
    }
    __syncthreads();                                           // B5

    // ---- phase 3: scatter (cursors advance to range ENDs) ----
    for (int j = tid; j < NN; j += NT) {
        uint4 p = pts[j];
        float x = __uint_as_float(p.x), y = __uint_as_float(p.y);
        int cx = min((int)(x * 0.125f), 63);
        int cy = min((int)(y * 0.125f), 63);
        unsigned q = atomicAdd(&cellidx[(cy << 6) | cx], 1u);
        cellpts[q] = (unsigned short)j;
        float cf = __uint_as_float(~p.z);
        int bk = 4095 - min((int)__fmul_rn(cf, 4096.0f), 4095);
        unsigned q2 = atomicAdd(&buckidx[bk], 1u);
        sortbuf[q2] = ((unsigned long long)p.z << 32) | (unsigned)j;
    }
    __syncthreads();                                           // B6
    // ranges now: [c ? idx[c-1] : 0, idx[c])

    // eval: 0=undet 1=kept 2=dead  (exact greedy dataflow semantics)
    auto eval = [&](int j) -> int {
        uint4 pj = pts[j];
        float x = __uint_as_float(pj.x), y = __uint_as_float(pj.y);
        unsigned kj = pj.z;
        int cx = min((int)(x * 0.125f), 63);
        int cy = min((int)(y * 0.125f), 63);
        float u = __fsub_rn(x, (float)(cx << 3));   // exact (Sterbenz)
        float v = __fsub_rn(y, (float)(cy << 3));
        int cx0 = (u < 4.0f) ? max(cx - 1, 0) : cx;
        int cy0 = (v < 4.0f) ? max(cy - 1, 0) : cy;
        int cx1 = min(cx0 + 1, 63), cy1 = min(cy0 + 1, 63);
        bool any_undet = false;
        for (int cyy = cy0; cyy <= cy1; ++cyy) {
            for (int cxx = cx0; cxx <= cx1; ++cxx) {
                int c = (cyy << 6) | cxx;
                unsigned s = c ? cellidx[c-1] : 0;
                unsigned e = cellidx[c];
                for (unsigned t = s; t < e; ++t) {
                    int m = cellpts[t];
                    uint4 pm = pts[m];   // single ds_read_b128
                    unsigned km = pm.z;
                    if (!(km < kj || (km == kj && m < j))) continue;   // earlier only
                    float dx  = __fsub_rn(__uint_as_float(pm.x), x);
                    float dyy = __fsub_rn(__uint_as_float(pm.y), y);
                    float d2  = __fadd_rn(__fmul_rn(dx, dx), __fmul_rn(dyy, dyy));
                    if (d2 < 16.0f) {
                        unsigned st = vstate[m << 2];   // fresh monotone read
                        if (st == 1) return 2;
                        if (st == 0) any_undet = true;
                    }
                }
            }
        }
        return any_undet ? 0 : 1;
    };

    // ---- phase 4: per-bucket insertion sort + round-0 eval + undet compaction ----
    for (int k = 0; k < 4; ++k) {
        int bkt = tid + (k << 10);
        unsigned s = bkt ? buckidx[bkt-1] : 0;
        unsigned e = buckidx[bkt];
        for (unsigned i = s + 1; i < e; ++i) {
            unsigned long long v = sortbuf[i];
            unsigned t2 = i;
            while (t2 > s && sortbuf[t2-1] > v) { sortbuf[t2] = sortbuf[t2-1]; --t2; }
            sortbuf[t2] = v;
        }
    }
    for (int k = 0; k < 4; ++k) {
        int j = tid + (k << 10);
        int r = eval(j);
        bool undet = (r == 0);
        if (!undet) vstate[j << 2] = (unsigned)r;
        unsigned long long mask = __ballot(undet ? 1 : 0);
        if (mask) {
            int leader = __ffsll(mask) - 1;
            unsigned old = 0;
            if (lane == leader) old = atomicAdd(&wlcnt, (unsigned)__popcll(mask));
            old = __shfl(old, leader);
            if (undet) wlA[old + __popcll(mask & ((1ull << lane) - 1ull))] = (unsigned short)j;
        }
    }
    __syncthreads();                                           // B7

    // ---- phase 5: single-wave barrier-free worklist drain ----
    if (wv == 0) {
        unsigned short* src = wlA;
        unsigned short* dst = wlB;
        int n = (int)wlcnt;
        while (n > 0) {
            int outn = 0;
            for (int i0 = 0; i0 < n; i0 += 64) {
                int i = i0 + lane;
                int j = (i < n) ? src[i] : -1;
                int r = 1;
                if (j >= 0) {
                    r = eval(j);
                    if (r) vstate[j << 2] = (unsigned)r;
                }
                unsigned long long undet = __ballot((j >= 0 && r == 0) ? 1 : 0);
                if (j >= 0 && r == 0)
                    dst[outn + __popcll(undet & ((1ull << lane) - 1ull))] = (unsigned short)j;
                outn += (int)__popcll(undet);
            }
            unsigned short* t = src; src = dst; dst = t;
            n = outn;
        }
    }
    __syncthreads();                                           // B8

    // ---- output: sorted peaks masked by keep ----
    for (int r = tid; r < NN; r += NT) {
        unsigned long long v = sortbuf[r];
        int oi = (int)(v & 0xFFFFu);
        uint4 p = pts[oi];
        bool kp = (p.w == 1u);
        float conf = __uint_as_float(~(unsigned)(v >> 32));
        bo[r*3+0] = kp ? __uint_as_float(p.x) : 0.0f;
        bo[r*3+1] = kp ? __uint_as_float(p.y) : 0.0f;
        bo[r*3+2] = kp ? conf : 0.0f;
    }
}

extern "C" void kernel_launch(void* const* d_in, const int* in_sizes, int n_in,
                              void* d_out, int out_size, void* d_ws, size_t ws_size,
                              hipStream_t stream) {
    const float* peaks = (const float*)d_in[0];
    float* out = (float*)d_out;
    const int B = in_sizes[0] / (NN * 3);
    DistanceNMS_kernel<<<B, NT, 0, stream>>>(peaks, out);
}

// Round 6
// 62.577 us; speedup vs baseline: 2.1391x; 2.1391x over previous
//
#include <hip/hip_runtime.h>

#define NN 4096
#define NT 1024
#define LISTCAP 2048
#define OVF_SENTINEL 0xFFFFFFFFFFFFFFFEull

__global__ __launch_bounds__(NT)
void DistanceNMS_kernel(const float* __restrict__ peaks, float* __restrict__ out)
{
    // ---- LDS (~148 KB) ----
    __shared__ uint4 cpk[NN];                   // 64K  cell-ordered {x_bits,y_bits,kb,origidx}
    __shared__ unsigned long long sortbuf[NN];  // 32K  (kb<<32)|origidx
    __shared__ unsigned cellidx[4096];          // 16K  count -> excl start -> end
    __shared__ unsigned buckidx[4096];          // 16K  bucket cursors; after B7: nbr lists [2048] u64
    __shared__ unsigned char state_[NN];        //  4K  by orig idx: 0=UNDET 1=KEPT 2=DEAD
    __shared__ unsigned short wl[NN];           //  8K  cell positions of undet points
    __shared__ unsigned short posOf[NN];        //  8K  origidx -> cell position
    __shared__ unsigned wavesumA[16], wavesumB[16];
    __shared__ unsigned wlcnt;

    const int tid  = threadIdx.x;
    const int lane = tid & 63;
    const int wv   = tid >> 6;
    const float* bp = peaks + (size_t)blockIdx.x * NN * 3;
    float* bo = out + (size_t)blockIdx.x * NN * 3;
    volatile unsigned char* vst = state_;
    unsigned long long* lists = (unsigned long long*)buckidx;

    // ---- phase 0: zero counters ----
    {
        int t4 = tid << 2;
        cellidx[t4]=0; cellidx[t4+1]=0; cellidx[t4+2]=0; cellidx[t4+3]=0;
        buckidx[t4]=0; buckidx[t4+1]=0; buckidx[t4+2]=0; buckidx[t4+3]=0;
        if (tid == 0) wlcnt = 0;
    }
    __syncthreads();                                           // B1

    // ---- phase 1: load to REGISTERS + count cells/buckets ----
    float xr[4], yr[4];
    unsigned kbr[4];
    #pragma unroll
    for (int k = 0; k < 4; ++k) {
        int j = tid + (k << 10);
        float x = bp[j*3+0], y = bp[j*3+1], cf = bp[j*3+2];
        xr[k] = x; yr[k] = y;
        kbr[k] = ~__float_as_uint(cf);          // conf>=0 -> ascending kb == descending conf
        state_[j] = 0;
        int cx = min((int)(x * 0.125f), 63);
        int cy = min((int)(y * 0.125f), 63);
        atomicAdd(&cellidx[(cy << 6) | cx], 1u);
        int bk = 4095 - min((int)__fmul_rn(cf, 4096.0f), 4095);  // exact monotone bucketing
        atomicAdd(&buckidx[bk], 1u);
    }
    __syncthreads();                                           // B2

    // ---- phase 2: dual in-place exclusive scan ----
    {
        int t4 = tid << 2;
        unsigned a0=cellidx[t4], a1=cellidx[t4+1], a2=cellidx[t4+2], a3=cellidx[t4+3];
        unsigned b0=buckidx[t4], b1=buckidx[t4+1], b2=buckidx[t4+2], b3=buckidx[t4+3];
        unsigned sa = a0+a1+a2+a3, sb = b0+b1+b2+b3;
        unsigned ia = sa, ib = sb;
        for (int off = 1; off < 64; off <<= 1) {
            unsigned na = __shfl_up(ia, off);
            unsigned nb = __shfl_up(ib, off);
            if (lane >= off) { ia += na; ib += nb; }
        }
        if (lane == 63) { wavesumA[wv] = ia; wavesumB[wv] = ib; }
        __syncthreads();                                       // B3
        if (tid == 0) {
            unsigned acc = 0;
            for (int i = 0; i < 16; ++i) { unsigned t = wavesumA[i]; wavesumA[i] = acc; acc += t; }
            acc = 0;
            for (int i = 0; i < 16; ++i) { unsigned t = wavesumB[i]; wavesumB[i] = acc; acc += t; }
        }
        __syncthreads();                                       // B4
        unsigned baseA = wavesumA[wv] + (ia - sa);
        unsigned baseB = wavesumB[wv] + (ib - sb);
        cellidx[t4]=baseA; cellidx[t4+1]=baseA+a0; cellidx[t4+2]=baseA+a0+a1; cellidx[t4+3]=baseA+a0+a1+a2;
        buckidx[t4]=baseB; buckidx[t4+1]=baseB+b0; buckidx[t4+2]=baseB+b0+b1; buckidx[t4+3]=baseB+b0+b1+b2;
    }
    __syncthreads();                                           // B5

    // ---- phase 3: scatter from registers (cursors advance to range ENDs) ----
    #pragma unroll
    for (int k = 0; k < 4; ++k) {
        int j = tid + (k << 10);
        float x = xr[k], y = yr[k];
        int cx = min((int)(x * 0.125f), 63);
        int cy = min((int)(y * 0.125f), 63);
        unsigned q = atomicAdd(&cellidx[(cy << 6) | cx], 1u);
        cpk[q] = make_uint4(__float_as_uint(x), __float_as_uint(y), kbr[k], (unsigned)j);
        posOf[j] = (unsigned short)q;
        float cf = __uint_as_float(~kbr[k]);
        int bk = 4095 - min((int)__fmul_rn(cf, 4096.0f), 4095);
        unsigned q2 = atomicAdd(&buckidx[bk], 1u);
        sortbuf[q2] = ((unsigned long long)kbr[k] << 32) | (unsigned)j;
    }
    __syncthreads();                                           // B6
    // ranges now: [c ? idx[c-1] : 0, idx[c])

    // ---- phase 4: per-bucket insertion sort (unique u64 keys -> deterministic stable order) ----
    #pragma unroll
    for (int k = 0; k < 4; ++k) {
        int bkt = tid + (k << 10);
        unsigned s = bkt ? buckidx[bkt-1] : 0;
        unsigned e = buckidx[bkt];
        for (unsigned i = s + 1; i < e; ++i) {
            unsigned long long v = sortbuf[i];
            unsigned t2 = i;
            while (t2 > s && sortbuf[t2-1] > v) { sortbuf[t2] = sortbuf[t2-1]; --t2; }
            sortbuf[t2] = v;
        }
    }
    __syncthreads();                                           // B7: buckidx region now free -> lists

    // eval: 0=undet 1=kept 2=dead (exact greedy dataflow; monotone final states)
    auto eval = [&](int t, bool build, unsigned long long &nbrpack, bool &ovf) -> int {
        uint4 pj = cpk[t];
        float x = __uint_as_float(pj.x), y = __uint_as_float(pj.y);
        unsigned kj = pj.z, jj = pj.w;
        int cx = min((int)(x * 0.125f), 63);
        int cy = min((int)(y * 0.125f), 63);
        float u = __fsub_rn(x, (float)(cx << 3));   // exact (Sterbenz)
        float v = __fsub_rn(y, (float)(cy << 3));
        int cx0 = (u < 4.0f) ? max(cx - 1, 0) : cx;
        int cy0 = (v < 4.0f) ? max(cy - 1, 0) : cy;
        int cx1 = min(cx0 + 1, 63), cy1 = min(cy0 + 1, 63);
        int nn_ = 0; nbrpack = ~0ull; ovf = false;
        bool anyundet = false;
        for (int cyy = cy0; cyy <= cy1; ++cyy) {
            for (int cxx = cx0; cxx <= cx1; ++cxx) {
                int c = (cyy << 6) | cxx;
                unsigned s = c ? cellidx[c-1] : 0;
                unsigned e = cellidx[c];
                for (unsigned q = s; q < e; ++q) {
                    uint4 pm = cpk[q];   // one ds_read_b128; adjacent lanes broadcast-overlap
                    if (!(pm.z < kj || (pm.z == kj && pm.w < jj))) continue;   // earlier only
                    float dx  = __fsub_rn(__uint_as_float(pm.x), x);
                    float dyy = __fsub_rn(__uint_as_float(pm.y), y);
                    float d2  = __fadd_rn(__fmul_rn(dx, dx), __fmul_rn(dyy, dyy));
                    if (d2 < 16.0f) {
                        unsigned char st = vst[pm.w];
                        if (st == 1) return 2;          // final -> safe
                        if (st == 0) {
                            anyundet = true;
                            if (build) {
                                if (nn_ < 4) {
                                    nbrpack &= ~(0xFFFFull << (nn_ * 16));
                                    nbrpack |= ((unsigned long long)pm.w) << (nn_ * 16);
                                    ++nn_;
                                } else ovf = true;
                            }
                        }
                        // st==2: final dead -> never relevant again
                    }
                }
            }
        }
        return anyundet ? 0 : 1;
    };

    // ---- phase 5: round 0 — full eval in CELL order + neighbor-list build ----
    #pragma unroll
    for (int k = 0; k < 4; ++k) {
        int t = tid + (k << 10);
        unsigned long long nbrpack; bool ovf;
        int r = eval(t, true, nbrpack, ovf);
        unsigned jj = cpk[t].w;
        if (r) state_[jj] = (unsigned char)r;
        else {
            unsigned slot = atomicAdd(&wlcnt, 1u);
            wl[slot] = (unsigned short)t;
            if (slot < LISTCAP) lists[slot] = ovf ? OVF_SENTINEL : nbrpack;
        }
    }
    __syncthreads();                                           // B8

    // ---- phase 6: multi-wave list-driven rounds (1 barrier per round) ----
    {
        int nwl = (int)wlcnt;
        unsigned live = 0;
        #pragma unroll
        for (int k = 0; k < 4; ++k) if (tid + (k << 10) < nwl) live |= (1u << k);

        while (true) {
            int mine = 0;
            #pragma unroll
            for (int k = 0; k < 4; ++k) {
                if (live & (1u << k)) {
                    int i = tid + (k << 10);
                    int t = wl[i];
                    unsigned jj = cpk[t].w;
                    int r;
                    unsigned long long L = (i < LISTCAP) ? lists[i] : OVF_SENTINEL;
                    if (L != OVF_SENTINEL) {
                        bool any1 = false, any0 = false;
                        #pragma unroll
                        for (int e = 0; e < 4; ++e) {
                            unsigned vv = (unsigned)((L >> (e * 16)) & 0xFFFFull);
                            if (vv < NN) {
                                unsigned char st = vst[vv];
                                any1 |= (st == 1);
                                any0 |= (st == 0);
                            }
                        }
                        r = any1 ? 2 : (any0 ? 0 : 1);
                    } else {
                        unsigned long long d_; bool o_;
                        r = eval(t, false, d_, o_);
                    }
                    if (r) { state_[jj] = (unsigned char)r; live &= ~(1u << k); }
                    else mine = 1;
                }
            }
            if (__syncthreads_count(mine) == 0) break;         // 1 barrier / round
        }
    }

    // ---- output: sorted peaks masked by keep ----
    for (int r4 = tid; r4 < NN; r4 += NT) {
        unsigned long long v = sortbuf[r4];
        unsigned oi = (unsigned)(v & 0xFFFFu);
        int t = posOf[oi];
        uint4 p = cpk[t];
        bool kp = (state_[oi] == 1);
        float conf = __uint_as_float(~(unsigned)(v >> 32));
        bo[r4*3+0] = kp ? __uint_as_float(p.x) : 0.0f;
        bo[r4*3+1] = kp ? __uint_as_float(p.y) : 0.0f;
        bo[r4*3+2] = kp ? conf : 0.0f;
    }
}

extern "C" void kernel_launch(void* const* d_in, const int* in_sizes, int n_in,
                              void* d_out, int out_size, void* d_ws, size_t ws_size,
                              hipStream_t stream) {
    const float* peaks = (const float*)d_in[0];
    float* out = (float*)d_out;
    const int B = in_sizes[0] / (NN * 3);
    DistanceNMS_kernel<<<B, NT, 0, stream>>>(peaks, out);
}